// Round 1
// 112.799 us; speedup vs baseline: 1.0080x; 1.0080x over previous
//
#include <hip/hip_runtime.h>

// Problem constants (from reference)
#define QQ 16
#define NQ 128
#define HH 256
#define P5 1024   // 4^5
#define LOG2E   1.44269504088896340f
#define K2LOG2E 2.88539008177792681f  // 2*log2(e)

// Raw v_exp_f32 (1 ulp, flush-denorm): avoids the __ocml_exp2_f32 wrapper,
// which adds ~5 VALU insts of denormal-range handling per call.
__device__ __forceinline__ float fast_exp2(float x) {
  return __builtin_amdgcn_exp2f(x);
}

// ---------------------------------------------------------------------------
// Block-wide sum over 256 threads (4 waves). All threads return the total.
// ---------------------------------------------------------------------------
__device__ __forceinline__ float block_sum256(float v, float* red, int t) {
#pragma unroll
  for (int o = 32; o > 0; o >>= 1) v += __shfl_down(v, o, 64);
  if ((t & 63) == 0) red[t >> 6] = v;
  __syncthreads();
  float r = red[0] + red[1] + red[2] + red[3];
  __syncthreads();
  return r;
}

// ---------------------------------------------------------------------------
// Prep kernel — unchanged from the verified version. 256 blocks x 256
// threads; block hb computes w2r[hb] = dot(Wx2[hb,:], rhs).
// Output (SoA, constants FOLDED):
//   ws[       h] = K2LOG2E * Wx1[0][h]
//   ws[ 256 + h] = K2LOG2E * Wx1[1][h]
//   ws[ 512 + h] = K2LOG2E * Wx1[2][h]
//   ws[ 768 + h] = K2LOG2E * bx1[h]
//   ws[1024 + h] = -2 * w2r[h]
//   ws[1280]     = b2r = dot(bx2, rhs)
// ---------------------------------------------------------------------------
__global__ __launch_bounds__(256) void prep_kernel(
    const float* __restrict__ eq,
    const float* __restrict__ q0, const float* __restrict__ q1,
    const float* __restrict__ q2, const float* __restrict__ q3,
    const float* __restrict__ q4,
    const float* __restrict__ Wx1, const float* __restrict__ bx1,
    const float* __restrict__ Wx2, const float* __restrict__ bx2,
    const float* __restrict__ Wq0, const float* __restrict__ bq0,
    const float* __restrict__ Wq1, const float* __restrict__ bq1,
    const float* __restrict__ Wq2, const float* __restrict__ bq2,
    const float* __restrict__ Wq3, const float* __restrict__ bq3,
    const float* __restrict__ Wq4, const float* __restrict__ bq4,
    float* __restrict__ ws) {
  __shared__ float sS[5][64];
  __shared__ float sRhs[P5];
  __shared__ float sPart[4][10];
  __shared__ float sAB[10];
  __shared__ float red[4];

  const int t = threadIdx.x;
  const int hb = blockIdx.x;
  const float c = -eq[0] * LOG2E;  // y = exp(-x^2*eq) = exp2(x^2 * c)

  const float* qs[5]  = {q0, q1, q2, q3, q4};
  const float* Wqs[5] = {Wq0, Wq1, Wq2, Wq3, Wq4};
  const float* bqs[5] = {bq0, bq1, bq2, bq3, bq4};

  // A_i = sum_r y*qx (v[2i]), B_i = sum_r y (v[2i+1])
  float v[10];
#pragma unroll
  for (int i = 0; i < 5; ++i) {
    float a = 0.f, b = 0.f;
    if (t < NQ) {
      float x = qs[i][t];
      float y = fast_exp2(x * x * c);
      a = y * x;
      b = y;
    }
    v[2 * i] = a;
    v[2 * i + 1] = b;
  }
#pragma unroll
  for (int k = 0; k < 10; ++k) {
    float s = v[k];
#pragma unroll
    for (int o = 32; o > 0; o >>= 1) s += __shfl_down(s, o, 64);
    if ((t & 63) == 0) sPart[t >> 6][k] = s;
  }
  __syncthreads();
  if (t < 10) sAB[t] = sPart[0][t] + sPart[1][t] + sPart[2][t] + sPart[3][t];
  __syncthreads();

  // s_i[j] = Wq_i[j]*A_i + bq_i[j]*B_i   (5 x 64)
  for (int k = t; k < 5 * 64; k += 256) {
    int i = k >> 6, j = k & 63;
    sS[i][j] = Wqs[i][j] * sAB[2 * i] + bqs[i][j] * sAB[2 * i + 1];
  }
  __syncthreads();

  // rhs[idx] = sum_x s0[b,x] s1[d,x] s2[f,x] s3[m,x] s4[v,x]
  for (int idx = t; idx < P5; idx += 256) {
    int b = (idx >> 8) & 3, d = (idx >> 6) & 3, f = (idx >> 4) & 3,
        m = (idx >> 2) & 3, w = idx & 3;
    float s = 0.f;
#pragma unroll
    for (int x = 0; x < QQ; ++x)
      s += sS[0][b * QQ + x] * sS[1][d * QQ + x] * sS[2][f * QQ + x] *
           sS[3][m * QQ + x] * sS[4][w * QQ + x];
    sRhs[idx] = s;
  }
  __syncthreads();

  // w2r[hb] = dot(Wx2[hb,:], rhs)
  const float* wrow = Wx2 + hb * P5;
  float p = 0.f;
#pragma unroll
  for (int k = 0; k < 4; ++k)
    p = fmaf(wrow[t + 256 * k], sRhs[t + 256 * k], p);
  p = block_sum256(p, red, t);

  if (t == 0) {
    ws[hb]          = K2LOG2E * Wx1[hb];
    ws[HH + hb]     = K2LOG2E * Wx1[HH + hb];
    ws[2 * HH + hb] = K2LOG2E * Wx1[2 * HH + hb];
    ws[3 * HH + hb] = K2LOG2E * bx1[hb];
    ws[4 * HH + hb] = -2.0f * p;
  }

  if (hb == 0) {
    float pb = 0.f;
    for (int j = t; j < P5; j += 256) pb = fmaf(bx2[j], sRhs[j], pb);
    pb = block_sum256(pb, red, t);
    if (t == 0) ws[5 * HH] = pb;
  }
}

// ---------------------------------------------------------------------------
// Main kernel: out[i] = CONST + sum_h wr'[h] / (1 + exp2(x_i.w'_h + b'_h))
// Round change vs verified 111-113us version: R=4 -> R=2 rows/lane
// (128 rows/block, 782 blocks instead of 391).
//   - tail balance: 391/256 CUs = 1.53 -> 30% of main's wall lost on the
//     2nd round; 782/256 = 3.05 rounds of half-size blocks smooths this.
//   - occupancy: ~2x resident waves/CU for latency hiding.
//   - LDS amortization still fine: 5x ds_read_b128 per 8 sigmoids
//     (~7.5 cy/sigmoid) vs 16 cy/sigmoid trans-pipe bound.
// Also: input row loads issued BEFORE the ws table staging so their HBM
// latency hides under table setup + butterfly.
// ---------------------------------------------------------------------------
__global__ __launch_bounds__(256) void main_kernel(
    const float* __restrict__ input, const float* __restrict__ ws,
    float* __restrict__ out, int n) {
  __shared__ float4 qtab[HH];         // {w0,w1,w2,b} (K2LOG2E folded)
  __shared__ float4 wtab4[HH / 4];    // -2*w2r
  __shared__ float red[4];
  __shared__ float sred[4][2][64];    // [wave][r][lane] partials

  const int t = threadIdx.x;
  const int lane = t & 63;
  const int wv = t >> 6;

  // ---- issue row loads first (independent of prep output) ----
  const int row0 = blockIdx.x * 128;
  float x0[2], x1[2], x2[2], acc[2];
#pragma unroll
  for (int r = 0; r < 2; ++r) {
    const int row = row0 + r * 64 + lane;
    x0[r] = x1[r] = x2[r] = 0.f;
    if (row < n) {
      x0[r] = input[row * 3 + 0];
      x1[r] = input[row * 3 + 1];
      x2[r] = input[row * 3 + 2];
    }
    acc[r] = 0.f;
  }

  // ---- stage table (thread t owns h = t; coalesced global reads) ----
  const float w0 = ws[t], w1 = ws[HH + t], w2 = ws[2 * HH + t];
  const float bb = ws[3 * HH + t], wr = ws[4 * HH + t];
  qtab[t] = make_float4(w0, w1, w2, bb);
  ((float*)wtab4)[t] = wr;

  // butterfly Sum wr within each wave; combine across waves via red[]
  float s = wr;
#pragma unroll
  for (int o = 32; o > 0; o >>= 1) s += __shfl_xor(s, o, 64);
  if (lane == 0) red[wv] = s;
  __syncthreads();  // covers qtab/wtab4/red
  const float CONST = fmaf(-0.5f, (red[0] + red[1]) + (red[2] + red[3]),
                           ws[5 * HH]);

  // ---- 2 rows per lane (same 128 rows for all 4 waves; h differs) ----
  const int hbase = wv * 64;
#pragma unroll 4
  for (int j = 0; j < 16; ++j) {
    const float4 wq = wtab4[wv * 16 + j];
    const float wrv[4] = {wq.x, wq.y, wq.z, wq.w};
#pragma unroll
    for (int u = 0; u < 4; ++u) {
      const float4 q = qtab[hbase + j * 4 + u];
#pragma unroll
      for (int r = 0; r < 2; ++r) {
        float a = fmaf(q.z, x2[r], fmaf(q.y, x1[r], fmaf(q.x, x0[r], q.w)));
        float rc = __builtin_amdgcn_rcpf(fast_exp2(a) + 1.0f);  // inf -> 0
        acc[r] = fmaf(wrv[u], rc, acc[r]);
      }
    }
  }

  // ---- combine the 4 waves' h-partials ----
#pragma unroll
  for (int r = 0; r < 2; ++r) sred[wv][r][lane] = acc[r];
  __syncthreads();

  if (t < 128) {  // thread t finalizes row group rr = t>>6, lane = t&63
    const int rr = t >> 6;
    const int row = row0 + rr * 64 + lane;
    if (row < n) {
      float sum = (sred[0][rr][lane] + sred[1][rr][lane]) +
                  (sred[2][rr][lane] + sred[3][rr][lane]);
      out[row] = sum + CONST;
    }
  }
}

// ---------------------------------------------------------------------------
extern "C" void kernel_launch(void* const* d_in, const int* in_sizes, int n_in,
                              void* d_out, int out_size, void* d_ws,
                              size_t ws_size, hipStream_t stream) {
  const float* input = (const float*)d_in[0];
  const float* eq    = (const float*)d_in[1];
  const float* q0    = (const float*)d_in[2];
  const float* q1    = (const float*)d_in[3];
  const float* q2    = (const float*)d_in[4];
  const float* q3    = (const float*)d_in[5];
  const float* q4    = (const float*)d_in[6];
  const float* Wx1   = (const float*)d_in[7];
  const float* bx1   = (const float*)d_in[8];
  const float* Wx2   = (const float*)d_in[9];
  const float* bx2   = (const float*)d_in[10];
  const float* Wq0   = (const float*)d_in[11];
  const float* bq0   = (const float*)d_in[12];
  const float* Wq1   = (const float*)d_in[13];
  const float* bq1   = (const float*)d_in[14];
  const float* Wq2   = (const float*)d_in[15];
  const float* bq2   = (const float*)d_in[16];
  const float* Wq3   = (const float*)d_in[17];
  const float* bq3   = (const float*)d_in[18];
  const float* Wq4   = (const float*)d_in[19];
  const float* bq4   = (const float*)d_in[20];

  float* ws  = (float*)d_ws;
  float* out = (float*)d_out;
  const int n = in_sizes[0] / 3;  // N = 100000

  hipLaunchKernelGGL(prep_kernel, dim3(HH), dim3(256), 0, stream,
                     eq, q0, q1, q2, q3, q4, Wx1, bx1, Wx2, bx2,
                     Wq0, bq0, Wq1, bq1, Wq2, bq2, Wq3, bq3, Wq4, bq4, ws);

  const int blocks = (n + 127) / 128;  // 128 rows per block (R=2 per lane)
  hipLaunchKernelGGL(main_kernel, dim3(blocks), dim3(256), 0, stream,
                     input, ws, out, n);
}